// Round 11
// baseline (112.283 us; speedup 1.0000x reference)
//
#include <hip/hip_runtime.h>
#include <math.h>
#include <float.h>

// ChamferLoss: set1/set2 [8, 4096, 3] fp32 -> scalar
// out = (sum of per-point min dists, both directions) / (8*4096*4096)
//
// v11 = v10 + tree-fold, rep=4 diagnostic.
// Ledger (base 62.65us): v6b=11.2, v7=11.5, v10=11.2 us/pass -- buffering,
// barrier count, masks, queries/block ALL neutral. v9 counters: MFMA pipe at
// floor (3.4us), VALUBusy 64% (~9.2us/pass) vs ~3us modeled instr count.
// Two live theories: (a) unmodeled VALU instrs, (b) fold16's 8-deep serial
// min chain (+ cross-MFMA chaining on dm0/dm1) exposes VALU latency under
// barrier-lockstep waves. v11 tests (b): fold16 as depth-3 tree (same 8
// v_min3), and runs rep=4 so the intrinsic build's counters are finally
// visible (dispatch ~45us > 40us fills).
// Decode: k' = (dur - 62.65)/4. Fold-latency theory -> k' 7-9us, VALUBusy
// ~45%. Neutral -> k' ~11, counters route the next fix. rep=1 next round.
//
// Math (HW-validated v4-v10): d^2 = q2 + [p2 - 2 q.p] via one
// v_mfma_f32_32x32x16_f16 per 32x32 (point x query) tile, fp16 hi/lo split:
//   A (all 64 lanes, same 16B): [phx,phy,phz, plx,ply,plz, p2h,p2l]
//   B k0-7:  [-2qhx,-2qhy,-2qhz, -2qhx,-2qhy,-2qhz, 1, 1]
//   B k8-15: [-2qlx,-2qly,-2qlz, 0,0,0,0,0]   (zeros kill A k11-15 junk)
// = p2h+p2l - 2qh.(ph+pl) - 2ql.ph  (drops ql.pl ~2^-24 rel).
// C/D: col=lane&31 = query; min over point-rows = reg folds + shfl_xor(32).

#define NPTS 4096

typedef __attribute__((ext_vector_type(8)))  _Float16 f16x8;
typedef __attribute__((ext_vector_type(16))) float    f32x16;

static __device__ __forceinline__ unsigned h2u(_Float16 h) {
    return (unsigned)__builtin_bit_cast(unsigned short, h);
}
static __device__ __forceinline__ unsigned pack2(unsigned a, unsigned b) {
    return (a & 0xFFFFu) | (b << 16);
}
static __device__ __forceinline__ uint4 packpt(float x, float y, float z) {
    const _Float16 hx = (_Float16)x, hy = (_Float16)y, hz = (_Float16)z;
    const _Float16 lx = (_Float16)(x - (float)hx);
    const _Float16 ly = (_Float16)(y - (float)hy);
    const _Float16 lz = (_Float16)(z - (float)hz);
    const float p2 = fmaf(x, x, fmaf(y, y, z * z));
    const _Float16 p2h = (_Float16)p2;
    const _Float16 p2l = (_Float16)(p2 - (float)p2h);
    return make_uint4(pack2(h2u(hx),  h2u(hy)),
                      pack2(h2u(hz),  h2u(lx)),
                      pack2(h2u(ly),  h2u(lz)),
                      pack2(h2u(p2h), h2u(p2l)));
}

__device__ __forceinline__ float fold16(const f32x16 c, float m) {
    // 8 x v_min3_f32, dependency DEPTH 3 (was 8): breaks the serial chain
    // that coupled consecutive MFMAs through the running min.
    const float a = fminf(fminf(c[0],  c[1]),  c[2]);
    const float b = fminf(fminf(c[3],  c[4]),  c[5]);
    const float d = fminf(fminf(c[6],  c[7]),  c[8]);
    const float e = fminf(fminf(c[9],  c[10]), c[11]);
    const float f = fminf(fminf(c[12], c[13]), c[14]);
    const float g = fminf(fminf(a, b), d);
    const float h = fminf(fminf(e, f), c[15]);
    return fminf(fminf(g, h), m);
}

__global__ __launch_bounds__(512, 4)
void chamfer_fused(const float* __restrict__ set1,
                   const float* __restrict__ set2,
                   float* __restrict__ out)
{
    __shared__ uint4 buf[2][1024];        // 32 KB; head of buf[0] reused as part[]

    const int blk = blockIdx.x & 1023;    // rep=4: higher bits repeat the work
    const int dir = blk >> 9;             // 0: q=set1 db=set2, 1: swapped
    const int rem = blk & 511;
    const int b   = rem >> 6;             // batch 0..7
    const int qc  = rem & 63;             // 64-query chunk 0..63

    const float* __restrict__ Q  = (dir ? set2 : set1) + (size_t)b * NPTS * 3;
    const float* __restrict__ DB = (dir ? set1 : set2) + (size_t)b * NPTS * 3;

    const int t    = threadIdx.x;
    const int lane = t & 63;
    const int w    = t >> 6;              // wave 0..7
    const int col  = lane & 31;
    const int half = lane >> 5;           // 0: B supplies k0-7, 1: k8-15
    const int qbase = qc * 64;

    // ---- B-frags: 2 query tiles, built per-lane from raw floats ----
    f16x8 Bf0, Bf1;
    #pragma unroll
    for (int j = 0; j < 2; ++j) {
        const float* qp = Q + (size_t)(qbase + j * 32 + col) * 3;
        const float qx = qp[0], qy = qp[1], qz = qp[2];
        const _Float16 hx = (_Float16)qx, hy = (_Float16)qy, hz = (_Float16)qz;
        uint4 bv;
        if (!half) {
            const unsigned mx = h2u((_Float16)(-2.0f * (float)hx));
            const unsigned my = h2u((_Float16)(-2.0f * (float)hy));
            const unsigned mz = h2u((_Float16)(-2.0f * (float)hz));
            const unsigned one = 0x3C00u;               // fp16 1.0
            bv = make_uint4(pack2(mx, my), pack2(mz, mx),
                            pack2(my, mz), pack2(one, one));
        } else {
            const unsigned mx = h2u((_Float16)(-2.0f * (qx - (float)hx)));
            const unsigned my = h2u((_Float16)(-2.0f * (qy - (float)hy)));
            const unsigned mz = h2u((_Float16)(-2.0f * (qz - (float)hz)));
            bv = make_uint4(pack2(mx, my), pack2(mz, 0), 0u, 0u);
        }
        if (j == 0) Bf0 = __builtin_bit_cast(f16x8, bv);
        else        Bf1 = __builtin_bit_cast(f16x8, bv);
    }

    // ---- stage half 0 (1024 points, 2 per thread) ----
    {
        const float* s = DB + 3 * t;
        buf[0][t]       = packpt(s[0], s[1], s[2]);
        const float* s2 = DB + 3 * (t + 512);
        buf[0][t + 512] = packpt(s2[0], s2[1], s2[2]);
    }
    __syncthreads();

    const f32x16 z16 = {0,0,0,0,0,0,0,0,0,0,0,0,0,0,0,0};
    float dm0 = FLT_MAX, dm1 = FLT_MAX;

    // ---- 4 phases: compute buf[h] (4 tiles/wave) || stage buf[h+1] ----
    for (int h = 0; h < 4; ++h) {
        // A-frags: ds_read_b128 results feed MFMA directly (no VALU rebuild)
        const f16x8* __restrict__ fb =
            (const f16x8*)&buf[h & 1][w * 128 + col];
        const f16x8 a0 = fb[0];
        const f16x8 a1 = fb[32];
        const f16x8 a2 = fb[64];
        const f16x8 a3 = fb[96];

        // issue next-half global loads early (latency hides under MFMA)
        float sx0 = 0, sy0 = 0, sz0 = 0, sx1 = 0, sy1 = 0, sz1 = 0;
        if (h < 3) {
            const float* s = DB + 3 * ((h + 1) * 1024 + t);
            sx0 = s[0]; sy0 = s[1]; sz0 = s[2];
            const float* s2 = s + 3 * 512;
            sx1 = s2[0]; sy1 = s2[1]; sz1 = s2[2];
        }

        f32x16 c;
        c = __builtin_amdgcn_mfma_f32_32x32x16_f16(a0, Bf0, z16, 0, 0, 0);
        dm0 = fold16(c, dm0);
        c = __builtin_amdgcn_mfma_f32_32x32x16_f16(a0, Bf1, z16, 0, 0, 0);
        dm1 = fold16(c, dm1);
        c = __builtin_amdgcn_mfma_f32_32x32x16_f16(a1, Bf0, z16, 0, 0, 0);
        dm0 = fold16(c, dm0);
        c = __builtin_amdgcn_mfma_f32_32x32x16_f16(a1, Bf1, z16, 0, 0, 0);
        dm1 = fold16(c, dm1);
        c = __builtin_amdgcn_mfma_f32_32x32x16_f16(a2, Bf0, z16, 0, 0, 0);
        dm0 = fold16(c, dm0);
        c = __builtin_amdgcn_mfma_f32_32x32x16_f16(a2, Bf1, z16, 0, 0, 0);
        dm1 = fold16(c, dm1);
        c = __builtin_amdgcn_mfma_f32_32x32x16_f16(a3, Bf0, z16, 0, 0, 0);
        dm0 = fold16(c, dm0);
        c = __builtin_amdgcn_mfma_f32_32x32x16_f16(a3, Bf1, z16, 0, 0, 0);
        dm1 = fold16(c, dm1);

        // pack + write next half (write-late; drains at the barrier)
        if (h < 3) {
            buf[(h + 1) & 1][t]       = packpt(sx0, sy0, sz0);
            buf[(h + 1) & 1][t + 512] = packpt(sx1, sy1, sz1);
        }
        __syncthreads();
    }

    // ---- combine row-halves; reuse buf LDS as part[8][64] ----
    const float v0 = fminf(dm0, __shfl_xor(dm0, 32));
    const float v1 = fminf(dm1, __shfl_xor(dm1, 32));
    float* part = (float*)&buf[0][0];     // 2 KB of the 32 KB buffer
    if (!half) {
        part[w * 64 + col]      = v0;
        part[w * 64 + 32 + col] = v1;
    }
    __syncthreads();

    // ---- final: min over 8 waves, add q2 (fp32 exact), sqrt, sum ----
    float dist = 0.0f;
    if (t < 64) {
        float m = part[t];
        #pragma unroll
        for (int ww = 1; ww < 8; ++ww)
            m = fminf(m, part[ww * 64 + t]);
        const float* qp = Q + (size_t)(qbase + t) * 3;
        const float q2 = fmaf(qp[0], qp[0], fmaf(qp[1], qp[1], qp[2] * qp[2]));
        dist = sqrtf(fmaxf(q2 + m, 0.0f));
    }
    #pragma unroll
    for (int off = 32; off > 0; off >>= 1)
        dist += __shfl_down(dist, off);
    if (t == 0)
        atomicAdd(out, dist * (1.0f / 536870912.0f));   // 1/(4 * 8*4096*4096)
}

extern "C" void kernel_launch(void* const* d_in, const int* in_sizes, int n_in,
                              void* d_out, int out_size, void* d_ws, size_t ws_size,
                              hipStream_t stream) {
    const float* s1 = (const float*)d_in[0];
    const float* s2 = (const float*)d_in[1];
    float* out = (float*)d_out;

    hipMemsetAsync(out, 0, sizeof(float), stream);  // d_out poisoned 0xAA each call
    chamfer_fused<<<dim3(4096), dim3(512), 0, stream>>>(s1, s2, out);
}

// Round 13
// 74.245 us; speedup vs baseline: 1.5123x; 1.5123x over previous
//
#include <hip/hip_runtime.h>
#include <math.h>
#include <float.h>

// ChamferLoss: set1/set2 [8, 4096, 3] fp32 -> scalar
// out = (sum of per-point min dists, both directions) / (8*4096*4096)
//
// v12b = v12 RESUBMITTED UNCHANGED (R12 was a container-infra failure, not
// a kernel verdict -- same signature as R5, where identical resubmission
// then ran clean and won). Theory/prediction from R11 stand:
// v11 rep=4 counters (intrinsic build): MFMA pipe at exact floor (22% util
// = 8.0k cyc/pass/CU = 1024 MFMA x 8cyc); VALU 19.2k cyc/pass/CU of which
// fold = 16.4k (8 v_min3/MFMA -- theoretical minimum for min-of-17, the
// formulation's hard floor 6.8us/pass). Remaining removable VALU: packpt
// (~30 cvt/point) re-executed by 64 blocks on identical points. Fix: pack
// once in a 256-block pre-kernel into d_ws (1 MB); main kernel staging is
// a pure uint4 global->reg->ds_write copy (no cvt, shorter dep chains).
// Target k 11.2 -> 8.5-10us. If >= 73.5 total: fold-floor reached, declare
// roofline (base 62.65 + fold 6.8 + overlap/pack ~1.5 = ~71us limit).
//
// Math (HW-validated v4-v11): d^2 = q2 + [p2 - 2 q.p] via one
// v_mfma_f32_32x32x16_f16 per 32x32 (point x query) tile, fp16 hi/lo split:
//   A (all 64 lanes, same 16B): [phx,phy,phz, plx,ply,plz, p2h,p2l]
//   B k0-7:  [-2qhx,-2qhy,-2qhz, -2qhx,-2qhy,-2qhz, 1, 1]
//   B k8-15: [-2qlx,-2qly,-2qlz, 0,0,0,0,0]   (zeros kill A k11-15 junk)
// = p2h+p2l - 2qh.(ph+pl) - 2ql.ph  (drops ql.pl ~2^-24 rel).
// C/D: col=lane&31 = query; min over point-rows = reg folds + shfl_xor(32).

#define NPTS 4096
#define NTOT 65536            // 2 sets * 8 * 4096

typedef __attribute__((ext_vector_type(8)))  _Float16 f16x8;
typedef __attribute__((ext_vector_type(16))) float    f32x16;

static __device__ __forceinline__ unsigned h2u(_Float16 h) {
    return (unsigned)__builtin_bit_cast(unsigned short, h);
}
static __device__ __forceinline__ unsigned pack2(unsigned a, unsigned b) {
    return (a & 0xFFFFu) | (b << 16);
}
static __device__ __forceinline__ uint4 packpt(float x, float y, float z) {
    const _Float16 hx = (_Float16)x, hy = (_Float16)y, hz = (_Float16)z;
    const _Float16 lx = (_Float16)(x - (float)hx);
    const _Float16 ly = (_Float16)(y - (float)hy);
    const _Float16 lz = (_Float16)(z - (float)hz);
    const float p2 = fmaf(x, x, fmaf(y, y, z * z));
    const _Float16 p2h = (_Float16)p2;
    const _Float16 p2l = (_Float16)(p2 - (float)p2h);
    return make_uint4(pack2(h2u(hx),  h2u(hy)),
                      pack2(h2u(hz),  h2u(lx)),
                      pack2(h2u(ly),  h2u(lz)),
                      pack2(h2u(p2h), h2u(p2l)));
}

__global__ __launch_bounds__(256)
void pack_pts(const float* __restrict__ set1, const float* __restrict__ set2,
              uint4* __restrict__ pk)
{
    const int i = blockIdx.x * 256 + threadIdx.x;     // 0..65535
    const float* __restrict__ src = (i < NTOT / 2) ? set1 : set2;
    const int idx = i & (NTOT / 2 - 1);
    pk[i] = packpt(src[3 * idx + 0], src[3 * idx + 1], src[3 * idx + 2]);
}

__device__ __forceinline__ float fold16(const f32x16 c, float m) {
    // 8 x v_min3_f32, dependency depth 3 (minimal op count for min-of-17)
    const float a = fminf(fminf(c[0],  c[1]),  c[2]);
    const float b = fminf(fminf(c[3],  c[4]),  c[5]);
    const float d = fminf(fminf(c[6],  c[7]),  c[8]);
    const float e = fminf(fminf(c[9],  c[10]), c[11]);
    const float f = fminf(fminf(c[12], c[13]), c[14]);
    const float g = fminf(fminf(a, b), d);
    const float h = fminf(fminf(e, f), c[15]);
    return fminf(fminf(g, h), m);
}

__global__ __launch_bounds__(512, 4)
void chamfer_fused(const uint4* __restrict__ pk,
                   const float* __restrict__ set1,
                   const float* __restrict__ set2,
                   float* __restrict__ out)
{
    __shared__ uint4 buf[2][1024];        // 32 KB; head of buf[0] reused as part[]

    const int blk = blockIdx.x;           // 0..1023
    const int dir = blk >> 9;             // 0: q=set1 db=set2, 1: swapped
    const int rem = blk & 511;
    const int b   = rem >> 6;             // batch 0..7
    const int qc  = rem & 63;             // 64-query chunk 0..63

    const float* __restrict__ Q   = (dir ? set2 : set1) + (size_t)b * NPTS * 3;
    const uint4* __restrict__ DBp = pk + (dir ? 0 : NTOT / 2) + (size_t)b * NPTS;

    const int t    = threadIdx.x;
    const int lane = t & 63;
    const int w    = t >> 6;              // wave 0..7
    const int col  = lane & 31;
    const int half = lane >> 5;           // 0: B supplies k0-7, 1: k8-15
    const int qbase = qc * 64;

    // ---- B-frags: 2 query tiles, built per-lane from raw floats ----
    f16x8 Bf0, Bf1;
    #pragma unroll
    for (int j = 0; j < 2; ++j) {
        const float* qp = Q + (size_t)(qbase + j * 32 + col) * 3;
        const float qx = qp[0], qy = qp[1], qz = qp[2];
        const _Float16 hx = (_Float16)qx, hy = (_Float16)qy, hz = (_Float16)qz;
        uint4 bv;
        if (!half) {
            const unsigned mx = h2u((_Float16)(-2.0f * (float)hx));
            const unsigned my = h2u((_Float16)(-2.0f * (float)hy));
            const unsigned mz = h2u((_Float16)(-2.0f * (float)hz));
            const unsigned one = 0x3C00u;               // fp16 1.0
            bv = make_uint4(pack2(mx, my), pack2(mz, mx),
                            pack2(my, mz), pack2(one, one));
        } else {
            const unsigned mx = h2u((_Float16)(-2.0f * (qx - (float)hx)));
            const unsigned my = h2u((_Float16)(-2.0f * (qy - (float)hy)));
            const unsigned mz = h2u((_Float16)(-2.0f * (qz - (float)hz)));
            bv = make_uint4(pack2(mx, my), pack2(mz, 0), 0u, 0u);
        }
        if (j == 0) Bf0 = __builtin_bit_cast(f16x8, bv);
        else        Bf1 = __builtin_bit_cast(f16x8, bv);
    }

    // ---- stage half 0: pure copy, no packing ----
    buf[0][t]       = DBp[t];
    buf[0][t + 512] = DBp[t + 512];
    __syncthreads();

    const f32x16 z16 = {0,0,0,0,0,0,0,0,0,0,0,0,0,0,0,0};
    float dm0 = FLT_MAX, dm1 = FLT_MAX;

    // ---- 4 phases: compute buf[h] (4 tiles/wave) || stage buf[h+1] ----
    for (int h = 0; h < 4; ++h) {
        // A-frags: ds_read_b128 results feed MFMA directly
        const f16x8* __restrict__ fb =
            (const f16x8*)&buf[h & 1][w * 128 + col];
        const f16x8 a0 = fb[0];
        const f16x8 a1 = fb[32];
        const f16x8 a2 = fb[64];
        const f16x8 a3 = fb[96];

        // issue next-half global loads early (latency hides under MFMA)
        uint4 n0 = make_uint4(0, 0, 0, 0), n1 = make_uint4(0, 0, 0, 0);
        if (h < 3) {
            n0 = DBp[(h + 1) * 1024 + t];
            n1 = DBp[(h + 1) * 1024 + 512 + t];
        }

        f32x16 c;
        c = __builtin_amdgcn_mfma_f32_32x32x16_f16(a0, Bf0, z16, 0, 0, 0);
        dm0 = fold16(c, dm0);
        c = __builtin_amdgcn_mfma_f32_32x32x16_f16(a0, Bf1, z16, 0, 0, 0);
        dm1 = fold16(c, dm1);
        c = __builtin_amdgcn_mfma_f32_32x32x16_f16(a1, Bf0, z16, 0, 0, 0);
        dm0 = fold16(c, dm0);
        c = __builtin_amdgcn_mfma_f32_32x32x16_f16(a1, Bf1, z16, 0, 0, 0);
        dm1 = fold16(c, dm1);
        c = __builtin_amdgcn_mfma_f32_32x32x16_f16(a2, Bf0, z16, 0, 0, 0);
        dm0 = fold16(c, dm0);
        c = __builtin_amdgcn_mfma_f32_32x32x16_f16(a2, Bf1, z16, 0, 0, 0);
        dm1 = fold16(c, dm1);
        c = __builtin_amdgcn_mfma_f32_32x32x16_f16(a3, Bf0, z16, 0, 0, 0);
        dm0 = fold16(c, dm0);
        c = __builtin_amdgcn_mfma_f32_32x32x16_f16(a3, Bf1, z16, 0, 0, 0);
        dm1 = fold16(c, dm1);

        // write next half (write-late; drains at the barrier)
        if (h < 3) {
            buf[(h + 1) & 1][t]       = n0;
            buf[(h + 1) & 1][t + 512] = n1;
        }
        __syncthreads();
    }

    // ---- combine row-halves; reuse buf LDS as part[8][64] ----
    const float v0 = fminf(dm0, __shfl_xor(dm0, 32));
    const float v1 = fminf(dm1, __shfl_xor(dm1, 32));
    float* part = (float*)&buf[0][0];     // 2 KB of the 32 KB buffer
    if (!half) {
        part[w * 64 + col]      = v0;
        part[w * 64 + 32 + col] = v1;
    }
    __syncthreads();

    // ---- final: min over 8 waves, add q2 (fp32 exact), sqrt, sum ----
    float dist = 0.0f;
    if (t < 64) {
        float m = part[t];
        #pragma unroll
        for (int ww = 1; ww < 8; ++ww)
            m = fminf(m, part[ww * 64 + t]);
        const float* qp = Q + (size_t)(qbase + t) * 3;
        const float q2 = fmaf(qp[0], qp[0], fmaf(qp[1], qp[1], qp[2] * qp[2]));
        dist = sqrtf(fmaxf(q2 + m, 0.0f));
    }
    #pragma unroll
    for (int off = 32; off > 0; off >>= 1)
        dist += __shfl_down(dist, off);
    if (t == 0)
        atomicAdd(out, dist * (1.0f / 134217728.0f));   // 1/(8*4096*4096)
}

extern "C" void kernel_launch(void* const* d_in, const int* in_sizes, int n_in,
                              void* d_out, int out_size, void* d_ws, size_t ws_size,
                              hipStream_t stream) {
    const float* s1 = (const float*)d_in[0];
    const float* s2 = (const float*)d_in[1];
    float* out = (float*)d_out;
    uint4* pk = (uint4*)d_ws;                       // 1 MB of workspace

    hipMemsetAsync(out, 0, sizeof(float), stream);  // d_out poisoned 0xAA each call
    pack_pts<<<dim3(NTOT / 256), dim3(256), 0, stream>>>(s1, s2, pk);
    chamfer_fused<<<dim3(1024), dim3(512), 0, stream>>>(pk, s1, s2, out);
}